// Round 1
// baseline (654.843 us; speedup 1.0000x reference)
//
#include <hip/hip_runtime.h>
#include <hip/hip_bf16.h>
#include <math.h>

// ---------------------------------------------------------------------------
// Real spherical harmonics, l_max = 8, Wikipedia convention, (l,m) lexicographic
// index = l*l + l + m. Output (N, 81) float32, row-major.
//
// R1: persistent pipelined version.
//   - Write-BW-bound op: 648 MB out vs ~6e8 FLOP -> roofline ~107 us @6.3 TB/s.
//   - fillBufferAligned hits 6.28 TB/s at 10% occupancy => saturation needs
//     CONTINUOUS store issue, not occupancy. Previous version serialized
//     load(~900cy) -> compute(~700cy) -> copy per block; store pipe idled
//     ~70% of the time (LDS caps residency at 7 waves/CU).
//   - Fix: grid-stride persistent blocks (7/CU), prefetch next tile's xyz
//     under current tile's compute, let stores of tile k drain (vmcnt queue)
//     under compute of tile k+1. Single LDS buffer: wave-internal lgkmcnt
//     ordering + single-wave-workgroup barrier (free) protect reuse.
// ---------------------------------------------------------------------------

#define LMAX 8
#define NSH  81        // (LMAX+1)^2
#define BPT  64        // points per tile == block size (one wave)
#define PERSIST_BLOCKS (7 * 256)   // 7 blocks/CU (LDS-capped) x 256 CUs

// ---- compile-time k(l,m) table (includes sqrt(2) for m>0) ------------------
constexpr double c_sqrt(double x) {
    double g = (x > 1.0) ? x : 1.0;
    for (int i = 0; i < 80; ++i) g = 0.5 * (g + x / g);
    return g;
}
constexpr double c_fact(int n) {
    double r = 1.0;
    for (int i = 2; i <= n; ++i) r *= (double)i;
    return r;
}
struct KTab {
    float k[LMAX + 1][LMAX + 1];   // k[l][m], m<=l
    constexpr KTab() : k{} {
        for (int l = 0; l <= LMAX; ++l)
            for (int m = 0; m <= l; ++m) {
                double v = c_sqrt((2.0 * l + 1.0) / (4.0 * 3.14159265358979323846)
                                  * c_fact(l - m) / c_fact(l + m));
                if (m > 0) v *= 1.41421356237309504880;   // sqrt(2)
                k[l][m] = (float)v;
            }
    }
};
constexpr KTab KT{};

__device__ __forceinline__ void compute_row(float x, float y, float z, float* row) {
    const float r2xy = x * x + y * y;
    const float r    = sqrtf(r2xy + z * z);
    const float rxy  = sqrtf(r2xy);
    const float ct   = z / r;
    const float st   = rxy / r;
    const float irxy = (rxy > 0.0f) ? (1.0f / rxy) : 0.0f;
    const float cp   = x * irxy;
    const float sp   = y * irxy;

    // cos(m phi), sin(m phi)
    float cm[LMAX + 1], sm[LMAX + 1];
    cm[0] = 1.0f; sm[0] = 0.0f;
#pragma unroll
    for (int m = 1; m <= LMAX; ++m) {
        cm[m] = cm[m - 1] * cp - sm[m - 1] * sp;
        sm[m] = sm[m - 1] * cp + cm[m - 1] * sp;
    }

    // associated Legendre (no Condon-Shortley), P[l][m], fully static indexing
    float P[LMAX + 1][LMAX + 1];
    P[0][0] = 1.0f;
#pragma unroll
    for (int m = 1; m <= LMAX; ++m)
        P[m][m] = (float)(2 * m - 1) * st * P[m - 1][m - 1];
#pragma unroll
    for (int m = 0; m < LMAX; ++m)
        P[m + 1][m] = (float)(2 * m + 1) * ct * P[m][m];
#pragma unroll
    for (int m = 0; m <= LMAX; ++m) {
#pragma unroll
        for (int l = m + 2; l <= LMAX; ++l) {
            P[l][m] = ((float)(2 * l - 1) * ct * P[l - 1][m]
                       - (float)(l + m - 1) * P[l - 2][m]) * (1.0f / (float)(l - m));
        }
    }

    // emit into LDS row: bank = (17*t + j) % 32 -> 2-way across 64 lanes (free)
#pragma unroll
    for (int l = 0; l <= LMAX; ++l) {
        const int base = l * l + l;
        row[base] = KT.k[l][0] * P[l][0];
#pragma unroll
        for (int m = 1; m <= l; ++m) {
            const float kp = KT.k[l][m] * P[l][m];
            row[base + m] = kp * cm[m];
            row[base - m] = kp * sm[m];
        }
    }
}

__global__ __launch_bounds__(BPT)
void sh_kernel(const float* __restrict__ xyz, float* __restrict__ out, int n) {
    __shared__ float lds[BPT * NSH];   // 20736 B -> 7 blocks/CU

    const int t      = threadIdx.x;
    const int ntiles = (n + BPT - 1) / BPT;

    int tile = blockIdx.x;
    if (tile >= ntiles) return;

    // ---- prefetch first tile's xyz ----
    float x = 0.0f, y = 0.0f, z = 1.0f;   // safe dummies for p >= n lanes
    {
        const int p = tile * BPT + t;
        if (p < n) {
            x = xyz[3 * p + 0];
            y = xyz[3 * p + 1];
            z = xyz[3 * p + 2];
        }
    }

    for (;;) {
        const int next_tile = tile + gridDim.x;

        // ---- issue next tile's loads NOW; latency hides under compute ----
        float nx = 0.0f, ny = 0.0f, nz = 1.0f;
        if (next_tile < ntiles) {
            const int np = next_tile * BPT + t;
            if (np < n) {
                nx = xyz[3 * np + 0];
                ny = xyz[3 * np + 1];
                nz = xyz[3 * np + 2];
            }
        }

        // ---- compute current tile into LDS (VALU, ~700 cy; hides prefetch
        //      latency AND drains the previous tile's store queue) ----
        compute_row(x, y, z, &lds[t * NSH]);
        __syncthreads();   // single-wave WG: compiles to lgkmcnt wait (+ free barrier)

        // ---- coalesced copy-out: contiguous [p0*81, (p0+valid)*81) ----
        const int p0    = tile * BPT;
        const int valid = (n - p0 < BPT) ? (n - p0) : BPT;
        float* op = out + (size_t)p0 * NSH;
        if (valid == BPT) {
            // 64*81*4 = 20736 B, 16B-aligned since p0 % 64 == 0
            float4* o4 = (float4*)op;
            const float4* l4 = (const float4*)lds;
#pragma unroll 4
            for (int i = t; i < BPT * NSH / 4; i += BPT)   // 1296 float4
                o4[i] = l4[i];          // stores stay in flight past loop exit
        } else {
            const int nf = valid * NSH;
            for (int i = t; i < nf; i += BPT)
                op[i] = lds[i];
        }

        if (next_tile >= ntiles) break;
        __syncthreads();   // LDS WAR: reads of tile k done before tile k+1 writes
        tile = next_tile;
        x = nx; y = ny; z = nz;
    }
}

extern "C" void kernel_launch(void* const* d_in, const int* in_sizes, int n_in,
                              void* d_out, int out_size, void* d_ws, size_t ws_size,
                              hipStream_t stream) {
    const float* xyz = (const float*)d_in[0];
    float*       out = (float*)d_out;
    const int n = in_sizes[0] / 3;
    const int ntiles = (n + BPT - 1) / BPT;
    const int grid = (ntiles < PERSIST_BLOCKS) ? ntiles : PERSIST_BLOCKS;
    if (grid > 0) {
        hipLaunchKernelGGL(sh_kernel, dim3(grid), dim3(BPT), 0, stream, xyz, out, n);
    }
}

// Round 2
// 653.804 us; speedup vs baseline: 1.0016x; 1.0016x over previous
//
#include <hip/hip_runtime.h>
#include <hip/hip_bf16.h>
#include <math.h>

// ---------------------------------------------------------------------------
// Real spherical harmonics, l_max = 8, Wikipedia convention, (l,m) lexicographic
// index = l*l + l + m. Output (N, 81) float32, row-major.
//
// R2: barrier-free wave-synchronous pipeline.
//   - dur_us decomposes as harness-poison-fill(413us, 2.59GB @6.28TB/s) +
//     sh_kernel(~237us). Kernel write roofline is ~107us @6.3TB/s.
//   - R1 post-mortem: __syncthreads() per tile emits s_waitcnt vmcnt(0)
//     (HIP barrier semantics drain ALL outstanding stores) -> every tile the
//     wave stalled on store completion; stores never pipelined. 33k cy/tile
//     observed vs ~900 cy of issue work.
//   - Fix: workgroup == 1 wave, so no __syncthreads needed. Intra-wave DS ops
//     execute in order in HW; compiler lgkmcnt covers VGPR hazards. Replace
//     barriers with zero-instruction compiler fences. Stores of tile k stay
//     in the vmcnt queue (~3 tiles deep) and drain under tile k+1 compute.
// ---------------------------------------------------------------------------

#define LMAX 8
#define NSH  81        // (LMAX+1)^2
#define BPT  64        // points per tile == block size (one wave)
#define PERSIST_BLOCKS (7 * 256)   // 7 blocks/CU (LDS-capped) x 256 CUs

// ---- compile-time k(l,m) table (includes sqrt(2) for m>0) ------------------
constexpr double c_sqrt(double x) {
    double g = (x > 1.0) ? x : 1.0;
    for (int i = 0; i < 80; ++i) g = 0.5 * (g + x / g);
    return g;
}
constexpr double c_fact(int n) {
    double r = 1.0;
    for (int i = 2; i <= n; ++i) r *= (double)i;
    return r;
}
struct KTab {
    float k[LMAX + 1][LMAX + 1];   // k[l][m], m<=l
    constexpr KTab() : k{} {
        for (int l = 0; l <= LMAX; ++l)
            for (int m = 0; m <= l; ++m) {
                double v = c_sqrt((2.0 * l + 1.0) / (4.0 * 3.14159265358979323846)
                                  * c_fact(l - m) / c_fact(l + m));
                if (m > 0) v *= 1.41421356237309504880;   // sqrt(2)
                k[l][m] = (float)v;
            }
    }
};
constexpr KTab KT{};

// zero-instruction ordering fence: blocks compiler reordering of LDS ops
// across it; HW executes same-wave DS ops in order, so no waitcnt needed.
__device__ __forceinline__ void wave_fence() {
    asm volatile("" ::: "memory");
    __builtin_amdgcn_wave_barrier();
}

__device__ __forceinline__ void compute_row(float x, float y, float z, float* row) {
    const float r2xy = x * x + y * y;
    const float r    = sqrtf(r2xy + z * z);
    const float rxy  = sqrtf(r2xy);
    const float ct   = z / r;
    const float st   = rxy / r;
    const float irxy = (rxy > 0.0f) ? (1.0f / rxy) : 0.0f;
    const float cp   = x * irxy;
    const float sp   = y * irxy;

    // cos(m phi), sin(m phi)
    float cm[LMAX + 1], sm[LMAX + 1];
    cm[0] = 1.0f; sm[0] = 0.0f;
#pragma unroll
    for (int m = 1; m <= LMAX; ++m) {
        cm[m] = cm[m - 1] * cp - sm[m - 1] * sp;
        sm[m] = sm[m - 1] * cp + cm[m - 1] * sp;
    }

    // associated Legendre (no Condon-Shortley), P[l][m], fully static indexing
    float P[LMAX + 1][LMAX + 1];
    P[0][0] = 1.0f;
#pragma unroll
    for (int m = 1; m <= LMAX; ++m)
        P[m][m] = (float)(2 * m - 1) * st * P[m - 1][m - 1];
#pragma unroll
    for (int m = 0; m < LMAX; ++m)
        P[m + 1][m] = (float)(2 * m + 1) * ct * P[m][m];
#pragma unroll
    for (int m = 0; m <= LMAX; ++m) {
#pragma unroll
        for (int l = m + 2; l <= LMAX; ++l) {
            P[l][m] = ((float)(2 * l - 1) * ct * P[l - 1][m]
                       - (float)(l + m - 1) * P[l - 2][m]) * (1.0f / (float)(l - m));
        }
    }

    // emit into LDS row: bank = (17*t + j) % 32 -> 2-way across 64 lanes (free)
#pragma unroll
    for (int l = 0; l <= LMAX; ++l) {
        const int base = l * l + l;
        row[base] = KT.k[l][0] * P[l][0];
#pragma unroll
        for (int m = 1; m <= l; ++m) {
            const float kp = KT.k[l][m] * P[l][m];
            row[base + m] = kp * cm[m];
            row[base - m] = kp * sm[m];
        }
    }
}

__global__ __launch_bounds__(BPT)
void sh_kernel(const float* __restrict__ xyz, float* __restrict__ out, int n) {
    __shared__ float lds[BPT * NSH];   // 20736 B -> 7 blocks/CU

    const int t      = threadIdx.x;
    const int ntiles = (n + BPT - 1) / BPT;

    int tile = blockIdx.x;
    if (tile >= ntiles) return;

    // ---- prefetch first tile's xyz ----
    float x = 0.0f, y = 0.0f, z = 1.0f;   // safe dummies for p >= n lanes
    {
        const int p = tile * BPT + t;
        if (p < n) {
            x = xyz[3 * p + 0];
            y = xyz[3 * p + 1];
            z = xyz[3 * p + 2];
        }
    }

    for (;;) {
        const int next_tile = tile + gridDim.x;

        // ---- issue next tile's loads NOW; latency hides under compute ----
        float nx = 0.0f, ny = 0.0f, nz = 1.0f;
        if (next_tile < ntiles) {
            const int np = next_tile * BPT + t;
            if (np < n) {
                nx = xyz[3 * np + 0];
                ny = xyz[3 * np + 1];
                nz = xyz[3 * np + 2];
            }
        }

        // ---- compute current tile into LDS (also drains prior tile's
        //      store queue via vmcnt backpressure, no explicit wait) ----
        compute_row(x, y, z, &lds[t * NSH]);
        wave_fence();   // order: ds_writes above before ds_reads below (HW in-order)

        // ---- coalesced copy-out: contiguous [p0*81, (p0+valid)*81) ----
        const int p0    = tile * BPT;
        const int valid = (n - p0 < BPT) ? (n - p0) : BPT;
        float* op = out + (size_t)p0 * NSH;
        if (valid == BPT) {
            // 64*81*4 = 20736 B, 16B-aligned since p0 % 64 == 0
            float4* o4 = (float4*)op;
            const float4* l4 = (const float4*)lds;
#pragma unroll 4
            for (int i = t; i < BPT * NSH / 4; i += BPT)   // 1296 float4
                o4[i] = l4[i];          // stores stay in flight past loop exit
        } else {
            const int nf = valid * NSH;
            for (int i = t; i < nf; i += BPT)
                op[i] = lds[i];
        }

        if (next_tile >= ntiles) break;
        wave_fence();   // order: ds_reads above before next tile's ds_writes
        tile = next_tile;
        x = nx; y = ny; z = nz;
    }
}

extern "C" void kernel_launch(void* const* d_in, const int* in_sizes, int n_in,
                              void* d_out, int out_size, void* d_ws, size_t ws_size,
                              hipStream_t stream) {
    const float* xyz = (const float*)d_in[0];
    float*       out = (float*)d_out;
    const int n = in_sizes[0] / 3;
    const int ntiles = (n + BPT - 1) / BPT;
    const int grid = (ntiles < PERSIST_BLOCKS) ? ntiles : PERSIST_BLOCKS;
    if (grid > 0) {
        hipLaunchKernelGGL(sh_kernel, dim3(grid), dim3(BPT), 0, stream, xyz, out, n);
    }
}